// Round 1
// baseline (2502.364 us; speedup 1.0000x reference)
//
#include <hip/hip_runtime.h>
#include <cmath>

#define HEADS 4
#define HID 32
#define IN_DIM 128
#define OUT_DIM 64
#define D1 (HEADS*HID)   /* 128 */
#define NEG_SLOPE 0.2f
#define BN_EPS 1e-5f

// ---- monotone float<->uint encoding for atomicMax on floats ----
__device__ __forceinline__ unsigned enc_f(float x){
  unsigned u = __float_as_uint(x);
  return (u & 0x80000000u) ? ~u : (u | 0x80000000u);
}
__device__ __forceinline__ float dec_f(unsigned u){
  unsigned v = (u & 0x80000000u) ? (u & 0x7FFFFFFFu) : ~u;
  return __uint_as_float(v);
}

// ---- K1: h1 = x @ W1 (no bias), fused per-head attention dots ----
// block = 128 threads, 4 nodes/block
__global__ void gemm1(const float* __restrict__ x, const float* __restrict__ W,
                      const float* __restrict__ a_s, const float* __restrict__ a_d,
                      float* __restrict__ h, float* __restrict__ asn,
                      float* __restrict__ adn, int n)
{
  __shared__ float xs[4][IN_DIM];
  int base = blockIdx.x * 4;
  int tid = threadIdx.x;   // 0..127 = output column
  #pragma unroll
  for (int i = 0; i < 4; ++i) {
    int node = base + i;
    xs[i][tid] = (node < n) ? x[(size_t)node*IN_DIM + tid] : 0.f;
  }
  __syncthreads();
  float acc[4] = {0.f,0.f,0.f,0.f};
  for (int k = 0; k < IN_DIM; ++k) {
    float w = W[k*D1 + tid];
    #pragma unroll
    for (int i = 0; i < 4; ++i) acc[i] = fmaf(xs[i][k], w, acc[i]);
  }
  int head = tid >> 5, d = tid & 31;
  float vs = a_s[head*HID + d], vd = a_d[head*HID + d];
  #pragma unroll
  for (int i = 0; i < 4; ++i) {
    int node = base + i;
    if (node >= n) break;
    h[(size_t)node*D1 + tid] = acc[i];
    float ps = acc[i]*vs, pd = acc[i]*vd;
    #pragma unroll
    for (int m = 16; m >= 1; m >>= 1) { ps += __shfl_xor(ps, m); pd += __shfl_xor(pd, m); }
    if (d == 0) { asn[node*HEADS + head] = ps; adn[node*HEADS + head] = pd; }
  }
}

// ---- K2: per (edge,head) alpha = leaky_relu(as[src]+ad[dst]); segment max ----
__global__ void edge_alpha1(const int* __restrict__ ei, int E, int n,
                            const float* __restrict__ asn, const float* __restrict__ adn,
                            float* __restrict__ alpha, unsigned* __restrict__ menc)
{
  int t = blockIdx.x*blockDim.x + threadIdx.x;
  int total = (E + n) * HEADS;
  if (t >= total) return;
  int e = t >> 2, head = t & 3;
  int s_, d_;
  if (e < E) { s_ = ei[e]; d_ = ei[E + e]; } else { s_ = d_ = e - E; }
  float al = asn[s_*HEADS + head] + adn[d_*HEADS + head];
  al = al > 0.f ? al : NEG_SLOPE*al;
  alpha[t] = al;
  atomicMax(&menc[d_*HEADS + head], enc_f(al));
}

// ---- K3: e = exp(alpha - m[dst]); segment sum ----
__global__ void edge_exp1(const int* __restrict__ ei, int E, int n,
                          const unsigned* __restrict__ menc,
                          float* __restrict__ alpha, float* __restrict__ ssum)
{
  int t = blockIdx.x*blockDim.x + threadIdx.x;
  int total = (E + n) * HEADS;
  if (t >= total) return;
  int e = t >> 2, head = t & 3;
  int d_ = (e < E) ? ei[E + e] : (e - E);
  float ev = __expf(alpha[t] - dec_f(menc[d_*HEADS + head]));
  alpha[t] = ev;
  atomicAdd(&ssum[d_*HEADS + head], ev);
}

// ---- K4: agg[dst] += h[src] * coef  (thread per (edge, col)) ----
__global__ void edge_agg1(const int* __restrict__ ei, int E, int n,
                          const float* __restrict__ evals, const float* __restrict__ ssum,
                          const float* __restrict__ h, float* __restrict__ agg)
{
  long long t = (long long)blockIdx.x*blockDim.x + threadIdx.x;
  if (t >= (long long)(E + n)*D1) return;
  int e = (int)(t >> 7), j = (int)(t & 127);
  int s_, d_;
  if (e < E) { s_ = ei[e]; d_ = ei[E + e]; } else { s_ = d_ = e - E; }
  int head = j >> 5;
  float coef = evals[e*HEADS + head] / (ssum[d_*HEADS + head] + 1e-16f);
  atomicAdd(&agg[(size_t)d_*D1 + j], h[(size_t)s_*D1 + j] * coef);
}

// ---- BN + ELU (in place), generic over feature width (power of 2) ----
__global__ void bn_elu(float* __restrict__ zio, const float* __restrict__ bias,
                       const float* __restrict__ g, const float* __restrict__ b,
                       const float* __restrict__ m, const float* __restrict__ v,
                       int total, int mask)
{
  int i = blockIdx.x*blockDim.x + threadIdx.x;
  if (i >= total) return;
  int j = i & mask;
  float val = zio[i] + bias[j];
  val = (val - m[j]) * rsqrtf(v[j] + BN_EPS) * g[j] + b[j];
  zio[i] = val > 0.f ? val : expm1f(val);
}

// ---- K6: h2 = z1 @ W2, fused attention dots (heads=1) ----
// block = 256 threads = 4 nodes x 64 cols (one wave per node)
__global__ void gemm2(const float* __restrict__ z, const float* __restrict__ W,
                      const float* __restrict__ a_s, const float* __restrict__ a_d,
                      float* __restrict__ h2, float* __restrict__ as2,
                      float* __restrict__ ad2, int n)
{
  __shared__ float zs[4][D1];
  int base = blockIdx.x * 4;
  int tid = threadIdx.x;
  for (int idx = tid; idx < 4*D1; idx += 256) {
    int i = idx >> 7, k = idx & 127;
    int node = base + i;
    zs[i][k] = (node < n) ? z[(size_t)node*D1 + k] : 0.f;
  }
  __syncthreads();
  int i = tid >> 6;       // node within block (== wave id)
  int j = tid & 63;       // output col (== lane)
  int node = base + i;
  float acc = 0.f;
  for (int k = 0; k < D1; ++k) acc = fmaf(zs[i][k], W[k*OUT_DIM + j], acc);
  if (node < n) {
    h2[(size_t)node*OUT_DIM + j] = acc;
    float ps = acc * a_s[j], pd = acc * a_d[j];
    #pragma unroll
    for (int m = 32; m >= 1; m >>= 1) { ps += __shfl_xor(ps, m); pd += __shfl_xor(pd, m); }
    if (j == 0) { as2[node] = ps; ad2[node] = pd; }
  }
}

// ---- K7/K8: layer-2 edge softmax (1 head) ----
__global__ void edge_alpha2(const int* __restrict__ ei, int E, int n,
                            const float* __restrict__ as2, const float* __restrict__ ad2,
                            float* __restrict__ alpha, unsigned* __restrict__ menc)
{
  int e = blockIdx.x*blockDim.x + threadIdx.x;
  if (e >= E + n) return;
  int s_, d_;
  if (e < E) { s_ = ei[e]; d_ = ei[E + e]; } else { s_ = d_ = e - E; }
  float al = as2[s_] + ad2[d_];
  al = al > 0.f ? al : NEG_SLOPE*al;
  alpha[e] = al;
  atomicMax(&menc[d_], enc_f(al));
}

__global__ void edge_exp2(const int* __restrict__ ei, int E, int n,
                          const unsigned* __restrict__ menc,
                          float* __restrict__ alpha, float* __restrict__ ssum)
{
  int e = blockIdx.x*blockDim.x + threadIdx.x;
  if (e >= E + n) return;
  int d_ = (e < E) ? ei[E + e] : (e - E);
  float ev = __expf(alpha[e] - dec_f(menc[d_]));
  alpha[e] = ev;
  atomicAdd(&ssum[d_], ev);
}

// ---- K9: layer-2 aggregation ----
__global__ void edge_agg2(const int* __restrict__ ei, int E, int n,
                          const float* __restrict__ evals, const float* __restrict__ ssum,
                          const float* __restrict__ h2, float* __restrict__ agg)
{
  long long t = (long long)blockIdx.x*blockDim.x + threadIdx.x;
  if (t >= (long long)(E + n)*OUT_DIM) return;
  int e = (int)(t >> 6), j = (int)(t & 63);
  int s_, d_;
  if (e < E) { s_ = ei[e]; d_ = ei[E + e]; } else { s_ = d_ = e - E; }
  float coef = evals[e] / (ssum[d_] + 1e-16f);
  atomicAdd(&agg[(size_t)d_*OUT_DIM + j], h2[(size_t)s_*OUT_DIM + j] * coef);
}

// ---- K11: pair MLP: sigmoid( elu([z[s],z[d]] @ hW1 + hb1) @ hW2 + hb2 ) ----
// block = 256 = 4 waves; one pair per wave per iteration
__global__ void pair_mlp(const int* __restrict__ src, const int* __restrict__ dst,
                         const float* __restrict__ z, const float* __restrict__ hW1,
                         const float* __restrict__ hb1, const float* __restrict__ hW2,
                         const float* __restrict__ hb2, float* __restrict__ out, int P)
{
  __shared__ float w1s[2*OUT_DIM][OUT_DIM];   // 32 KiB
  __shared__ float w2s[OUT_DIM];
  int tid = threadIdx.x;
  for (int idx = tid; idx < 2*OUT_DIM*OUT_DIM; idx += 256)
    w1s[idx >> 6][idx & 63] = hW1[idx];
  if (tid < OUT_DIM) w2s[tid] = hW2[tid];
  __syncthreads();
  int wave = tid >> 6, lane = tid & 63;
  float bias1 = hb1[lane];
  float b2v = hb2[0];
  int stride = gridDim.x * 4;
  for (int p = blockIdx.x*4 + wave; p < P; p += stride) {
    int sp = src[p], dp = dst[p];
    float zsv = z[(size_t)sp*OUT_DIM + lane];
    float zdv = z[(size_t)dp*OUT_DIM + lane];
    float acc = bias1;
    #pragma unroll
    for (int k = 0; k < 64; ++k) acc = fmaf(__shfl(zsv, k), w1s[k][lane], acc);
    #pragma unroll
    for (int k = 0; k < 64; ++k) acc = fmaf(__shfl(zdv, k), w1s[64+k][lane], acc);
    float hid = acc > 0.f ? acc : expm1f(acc);
    float pl = hid * w2s[lane];
    #pragma unroll
    for (int m = 32; m >= 1; m >>= 1) pl += __shfl_xor(pl, m);
    if (lane == 0) out[p] = 1.f / (1.f + __expf(-(pl + b2v)));
  }
}

extern "C" void kernel_launch(void* const* d_in, const int* in_sizes, int n_in,
                              void* d_out, int out_size, void* d_ws, size_t ws_size,
                              hipStream_t stream)
{
  const float* x    = (const float*)d_in[0];
  const int*   ei   = (const int*)d_in[1];
  const int*   src  = (const int*)d_in[2];
  const int*   dst  = (const int*)d_in[3];
  const float* W1   = (const float*)d_in[4];
  const float* a1s  = (const float*)d_in[5];
  const float* a1d  = (const float*)d_in[6];
  const float* b1   = (const float*)d_in[7];
  const float* bn1g = (const float*)d_in[8];
  const float* bn1b = (const float*)d_in[9];
  const float* bn1m = (const float*)d_in[10];
  const float* bn1v = (const float*)d_in[11];
  const float* W2   = (const float*)d_in[12];
  const float* a2s  = (const float*)d_in[13];
  const float* a2d  = (const float*)d_in[14];
  const float* b2   = (const float*)d_in[15];
  const float* bn2g = (const float*)d_in[16];
  const float* bn2b = (const float*)d_in[17];
  const float* bn2m = (const float*)d_in[18];
  const float* bn2v = (const float*)d_in[19];
  const float* hW1  = (const float*)d_in[20];
  const float* hb1  = (const float*)d_in[21];
  const float* hW2  = (const float*)d_in[22];
  const float* hb2  = (const float*)d_in[23];

  const int N  = in_sizes[0] / IN_DIM;
  const int E  = in_sizes[1] / 2;
  const int P  = in_sizes[2];
  const int Ep = E + N;

  // ---- workspace layout (floats), with aliasing ----
  float* ws = (float*)d_ws;
  float* h1     = ws;                          // N*128  (later: h2 = N*64)
  float* agg1   = h1   + (size_t)N*D1;         // N*128  (later: agg2/z2 = N*64)
  float* alpha1 = agg1 + (size_t)N*D1;         // Ep*4   (later: alpha2 = Ep)
  float* as1    = alpha1 + (size_t)Ep*HEADS;   // N*4
  float* ad1    = as1 + (size_t)N*HEADS;       // N*4
  unsigned* m1  = (unsigned*)(ad1 + (size_t)N*HEADS); // N*4
  float* s1     = (float*)(m1 + (size_t)N*HEADS);     // N*4
  float* as2    = s1 + (size_t)N*HEADS;        // N
  float* ad2    = as2 + N;                     // N
  unsigned* m2  = (unsigned*)(ad2 + N);        // N
  float* s2     = (float*)(m2 + N);            // N
  float* h2     = h1;       // reuse
  float* alpha2 = alpha1;   // reuse
  float* agg2   = agg1;     // reuse (z1 consumed by gemm2 before this is zeroed)

  // ---- layer 1 ----
  hipMemsetAsync(agg1, 0, (size_t)N*D1*sizeof(float), stream);
  hipMemsetAsync(m1,   0, (size_t)N*HEADS*sizeof(unsigned), stream);
  hipMemsetAsync(s1,   0, (size_t)N*HEADS*sizeof(float), stream);
  hipMemsetAsync(m2,   0, (size_t)N*sizeof(unsigned), stream);
  hipMemsetAsync(s2,   0, (size_t)N*sizeof(float), stream);

  gemm1<<<(N + 3)/4, 128, 0, stream>>>(x, W1, a1s, a1d, h1, as1, ad1, N);

  {
    int total = Ep * HEADS;
    int blocks = (total + 255) / 256;
    edge_alpha1<<<blocks, 256, 0, stream>>>(ei, E, N, as1, ad1, alpha1, m1);
    edge_exp1  <<<blocks, 256, 0, stream>>>(ei, E, N, m1, alpha1, s1);
  }
  {
    long long total = (long long)Ep * D1;
    int blocks = (int)((total + 255) / 256);
    edge_agg1<<<blocks, 256, 0, stream>>>(ei, E, N, alpha1, s1, h1, agg1);
  }
  bn_elu<<<(N*D1 + 255)/256, 256, 0, stream>>>(agg1, b1, bn1g, bn1b, bn1m, bn1v,
                                               N*D1, D1 - 1);

  // ---- layer 2 ----
  gemm2<<<(N + 3)/4, 256, 0, stream>>>(agg1, W2, a2s, a2d, h2, as2, ad2, N);

  hipMemsetAsync(agg2, 0, (size_t)N*OUT_DIM*sizeof(float), stream);  // after gemm2 read z1

  {
    int blocks = (Ep + 255) / 256;
    edge_alpha2<<<blocks, 256, 0, stream>>>(ei, E, N, as2, ad2, alpha2, m2);
    edge_exp2  <<<blocks, 256, 0, stream>>>(ei, E, N, m2, alpha2, s2);
  }
  {
    long long total = (long long)Ep * OUT_DIM;
    int blocks = (int)((total + 255) / 256);
    edge_agg2<<<blocks, 256, 0, stream>>>(ei, E, N, alpha2, s2, h2, agg2);
  }
  bn_elu<<<(N*OUT_DIM + 255)/256, 256, 0, stream>>>(agg2, b2, bn2g, bn2b, bn2m, bn2v,
                                                    N*OUT_DIM, OUT_DIM - 1);

  // ---- pair MLP head ----
  pair_mlp<<<4096, 256, 0, stream>>>(src, dst, agg2, hW1, hb1, hW2, hb2,
                                     (float*)d_out, P);
}